// Round 13
// baseline (63096.625 us; speedup 1.0000x reference)
//
#include <hip/hip_runtime.h>
#include <float.h>

constexpr int SEQ  = 128;   // sentence length T
constexpr int D    = 256;   // DIM / STATEDIM
constexpr int G    = 1024;  // 4*DIM gate width
constexpr int NREL = 26;    // REL_COUNT + 1
constexpr int NENT = 7;

typedef float v2f __attribute__((ext_vector_type(2)));
typedef float v4f __attribute__((ext_vector_type(4)));

// ---------------------------------------------------------------------------
// Generic strided transpose: out[k*rows + i] = in[i*in_stride + in_off + k]
// ---------------------------------------------------------------------------
__global__ void k_trans(const float* __restrict__ in, float* __restrict__ out,
                        int rows, int cols, int in_stride, int in_off)
{
    int idx = blockIdx.x * 256 + threadIdx.x;
    if (idx >= rows * cols) return;
    int i = idx % rows;
    int k = idx / rows;
    out[idx] = in[(size_t)i * in_stride + in_off + k];
}

// ---------------------------------------------------------------------------
// xg[t][j] = bih[j] + bhh[j] + sum_k wordvector[text[t]][k] * Wih[j][k]
// ---------------------------------------------------------------------------
__global__ __launch_bounds__(1024) void k_xg(
    const int* __restrict__ text, const float* __restrict__ wv,
    const float* __restrict__ Wih, const float* __restrict__ bih,
    const float* __restrict__ bhh, float* __restrict__ xg)
{
    int t = blockIdx.x, j = threadIdx.x;
    const float* x  = wv + (size_t)text[t] * D;
    const float* wr = Wih + (size_t)j * D;
    float acc = bih[j] + bhh[j];
    for (int k = 0; k < D; ++k) acc += x[k] * wr[k];
    xg[t * G + j] = acc;
}

// ---------------------------------------------------------------------------
// Sequential LSTM, one block per direction (grid=2), 1024 threads.
// ---------------------------------------------------------------------------
__global__ __launch_bounds__(1024) void k_lstm(
    const float* __restrict__ xgF, const float* __restrict__ xgB,
    const float* __restrict__ WHTF, const float* __restrict__ WHTB,
    float* __restrict__ wordin)
{
    int dir = blockIdx.x;
    const float* xg  = dir ? xgB  : xgF;
    const float* WHT = dir ? WHTB : WHTF;
    __shared__ float h[D], c[D], g[G];
    int j = threadIdx.x;
    if (j < D) { h[j] = 0.f; c[j] = 0.f; }
    __syncthreads();
    for (int s = 0; s < SEQ; ++s) {
        int t = dir ? (SEQ - 1 - s) : s;
        float acc = xg[t * G + j];
        for (int k = 0; k < D; ++k) acc += WHT[k * G + j] * h[k];
        g[j] = acc;
        __syncthreads();
        if (j < D) {
            float si = 1.f / (1.f + expf(-g[j]));
            float sf = 1.f / (1.f + expf(-g[D + j]));
            float gg = tanhf(g[2 * D + j]);
            float so = 1.f / (1.f + expf(-g[3 * D + j]));
            float cn = sf * c[j] + si * gg;
            float hn = so * tanhf(cn);
            c[j] = cn; h[j] = hn;
            wordin[t * (2 * D) + dir * D + j] = hn;
        }
        __syncthreads();
    }
}

// ---------------------------------------------------------------------------
// Parallel precompute after LSTM (TW/BW per word, RV per relation, EV per ent)
// ---------------------------------------------------------------------------
__global__ __launch_bounds__(256) void k_prep2(
    const float* __restrict__ wordin,
    const float* __restrict__ WTWT, const float* __restrict__ WBWT,
    const float* __restrict__ WTRT, const float* __restrict__ WBET,
    const float* __restrict__ relvec, const float* __restrict__ entvec,
    const float* __restrict__ btv, const float* __restrict__ bbv,
    float* __restrict__ TW, float* __restrict__ BW,
    float* __restrict__ RV, float* __restrict__ EV)
{
    int b = blockIdx.x, i = threadIdx.x;
    if (b < SEQ) {
        const float* w = wordin + b * (2 * D);
        float a1 = btv[i], a2 = bbv[i];
        for (int j = 0; j < 2 * D; ++j) {
            float wv = w[j];
            a1 += wv * WTWT[j * D + i];
            a2 += wv * WBWT[j * D + i];
        }
        TW[b * D + i] = a1;
        BW[b * D + i] = a2;
    } else if (b < SEQ + NREL) {
        int r = b - SEQ;
        const float* x = relvec + r * D;
        float a = 0.f;
        for (int k = 0; k < D; ++k) a += x[k] * WTRT[k * D + i];
        RV[r * D + i] = a;
    } else {
        int e = b - SEQ - NREL;
        const float* x = entvec + e * D;
        float a = 0.f;
        for (int k = 0; k < D; ++k) a += x[k] * WBET[k * D + i];
        EV[e * D + i] = a;
    }
}

// ---------------------------------------------------------------------------
// M1T[j*D + i] = sum_k WBGT[k*D+i] * Wtt[k*D+j]   (M1 = Wb_target @ Wtt)
// ---------------------------------------------------------------------------
__global__ __launch_bounds__(256) void k_m1(
    const float* __restrict__ WBGT, const float* __restrict__ Wtt,
    float* __restrict__ M1T)
{
    int j = blockIdx.x, i = threadIdx.x;
    float a = 0.f;
    for (int k = 0; k < D; ++k) a = fmaf(WBGT[k * D + i], Wtt[k * D + j], a);
    M1T[j * D + i] = a;
}

// c1[i] = sum_k WBGT[k*D+i] * btt[k]
__global__ __launch_bounds__(256) void k_c1(
    const float* __restrict__ WBGT, const float* __restrict__ btt,
    float* __restrict__ c1)
{
    int i = threadIdx.x;
    float a = 0.f;
    for (int k = 0; k < D; ++k) a = fmaf(WBGT[k * D + i], btt[k], a);
    c1[i] = a;
}

// ---------------------------------------------------------------------------
// Packs for the 2-tier bot weight matvec (512 threads, tid = h*256+i):
//  L2 tier  n=0..13 : f4 slot n*512 + tid    = Wb[i][768 + h*128 + 4n + c]
//                      (coalesced: adjacent lanes -> adjacent 16B)
//  LDS tier j=0..17 : f4 slot (w*18+j)*64+l  = Wb[i][768 + h*128 + 56 + 4j+c]
//                      (tid = w*64+l; conflict-free wave-contiguous layout)
// ---------------------------------------------------------------------------
__global__ __launch_bounds__(256) void k_packBg(
    const float* __restrict__ Wb, float* __restrict__ WGL)
{
    int f = blockIdx.x * 256 + threadIdx.x;      // 0..28671
    if (f >= 512 * 56) return;
    int f4 = f >> 2, c = f & 3;
    int tid = f4 & 511, n = f4 >> 9;
    int h = tid >> 8, i = tid & 255;
    WGL[f] = Wb[(size_t)i * (5 * D) + 3 * D + h * 128 + 4 * n + c];
}

__global__ __launch_bounds__(256) void k_packBl(
    const float* __restrict__ Wb, float* __restrict__ WLDS)
{
    int f = blockIdx.x * 256 + threadIdx.x;      // 0..36863
    if (f >= 512 * 72) return;
    int f4 = f >> 2, c = f & 3;
    int l = f4 & 63, rest = f4 >> 6;
    int j = rest % 18, w = rest / 18;
    int tid = w * 64 + l;
    int h = tid >> 8, i = tid & 255;
    WLDS[f] = Wb[(size_t)i * (5 * D) + 3 * D + h * 128 + 56 + 4 * j + c];
}

// ---------------------------------------------------------------------------
// Streamed split-k half-matvec (top steps): Wcol = W^T[k0*D + i] (k-major).
// unroll CAPPED at 8: R12's full unroll spiked register pressure here, which
// made the allocator demote long-lived values for the WHOLE kernel.
// ---------------------------------------------------------------------------
__device__ inline float mv_half(const float* __restrict__ Wcol,
                                const float* __restrict__ x)
{
    float a0 = 0.f, a1 = 0.f, a2 = 0.f, a3 = 0.f;
    #pragma unroll 8
    for (int kk = 0; kk < 128; kk += 4) {
        a0 = fmaf(Wcol[(kk + 0) * D], x[kk + 0], a0);
        a1 = fmaf(Wcol[(kk + 1) * D], x[kk + 1], a1);
        a2 = fmaf(Wcol[(kk + 2) * D], x[kk + 2], a2);
        a3 = fmaf(Wcol[(kk + 3) * D], x[kk + 3], a3);
    }
    return (a0 + a1) + (a2 + a3);
}

// ---------------------------------------------------------------------------
// Softmax + first-occurrence argmax over n values in lanes 0..n-1 of each
// W-lane group (reference-faithful: p = exp(l-max)/sum, argmax over p).
// ---------------------------------------------------------------------------
template<int W>
__device__ inline void grp_smax(float lv, int n, int lane, int& am, float& pm)
{
    float mx = lv;
    #pragma unroll
    for (int off = W / 2; off; off >>= 1) mx = fmaxf(mx, __shfl_xor(mx, off));
    float e  = (lane < n) ? expf(lv - mx) : 0.f;
    float se = e;
    #pragma unroll
    for (int off = W / 2; off; off >>= 1) se += __shfl_xor(se, off);
    float p  = (lane < n) ? (e / se) : -1.f;
    float q  = p;
    #pragma unroll
    for (int off = W / 2; off; off >>= 1) q = fmaxf(q, __shfl_xor(q, off));
    unsigned long long mask = __ballot(p == q);
    am = __ffsll((long long)mask) - 1;
    pm = q;
}

// FMA helpers: one float4 pair into two v2f accumulators
#define FMA_AB(Wv, Xv)                                                        \
    { v4f xx_ = (Xv);                                                         \
      A0 = __builtin_elementwise_fma((v2f){(Wv).x, (Wv).y},                   \
                                     (v2f){xx_.x, xx_.y}, A0);                \
      A1 = __builtin_elementwise_fma((v2f){(Wv).z, (Wv).w},                   \
                                     (v2f){xx_.z, xx_.w}, A1); }
#define FMA_CD(Wv, Xv)                                                        \
    { v4f xx_ = (Xv);                                                         \
      A2 = __builtin_elementwise_fma((v2f){(Wv).x, (Wv).y},                   \
                                     (v2f){xx_.x, xx_.y}, A2);                \
      A3 = __builtin_elementwise_fma((v2f){(Wv).z, (Wv).w},                   \
                                     (v2f){xx_.z, xx_.w}, A3); }

// one LDS weight chunk: 4 f4 weights x 4 f4 x-broadcast, then a fence
#define LC(j0)                                                                \
    { v4f la = wbase[(j0 + 0) * 64], lb = wbase[(j0 + 1) * 64],               \
          lc = wbase[(j0 + 2) * 64], ld = wbase[(j0 + 3) * 64];               \
      FMA_AB(la, xb[14 + j0 + 0]) FMA_CD(lb, xb[14 + j0 + 1])                 \
      FMA_AB(lc, xb[14 + j0 + 2]) FMA_CD(ld, xb[14 + j0 + 3])                 \
      __builtin_amdgcn_sched_barrier(0); }

// ---------------------------------------------------------------------------
// Sequential main kernel: 1 block, 512 threads = 8 waves = 2 waves/SIMD.
// R1-R12 ledger: ANY long-lived weight register array gets globally demoted
// to scratch when pressure spikes anywhere in the kernel -> per-step HBM
// reloads. This design holds ZERO weight registers: 18 f4 in LDS (147 KB,
// conflict-free) + 14 f4 re-streamed per step from an L2-resident pack via
// coalesced global_load_dwordx4 (pointer asm-pinned so LICM cannot hoist
// them into long-lived registers). Loads issue at step start, consumed after
// the LDS tier -> ~600 cy of LDS work hides L2 latency. Only scalars are
// live across the loop. Peak demand ~112 < 128-reg grant.
// ---------------------------------------------------------------------------
__global__ __launch_bounds__(512)
void k_mainB(
    const float* __restrict__ TW,   const float* __restrict__ BW,
    const float* __restrict__ RV,   const float* __restrict__ EV,
    const float* __restrict__ WTMT, const float* __restrict__ WTBT,
    const float* __restrict__ WBTT, const float* __restrict__ M1T,
    const float* __restrict__ c1v,  const float* __restrict__ WLDS,
    const float* __restrict__ WGL,
    const float* __restrict__ Wp,   const float* __restrict__ bp,
    const float* __restrict__ Wpl,  const float* __restrict__ bpl,
    const float* __restrict__ btb,  const float* __restrict__ bbt,
    float* __restrict__ out)
{
    const int tid  = threadIdx.x;
    const int lane = tid & 63;
    const int wv8  = tid >> 6;        // wave id 0..7
    const int lwv  = wv8 & 3;         // wave id within half
    const int h    = tid >> 8;        // k-half 0..1
    const int i    = tid & 255;       // output index
    const bool lower = (tid < 256);

    // --- LDS (161,312 B total) ---
    __shared__ __align__(16) float wlds[512 * 72];        // 147,456 B
    __shared__ __align__(16) float xbuf[2][D];
    __shared__ __align__(16) float psA[2][D];
    __shared__ __align__(16) float mem[D], outv[D];
    __shared__ __align__(16) float WrSh[NENT * D];
    __shared__ float lpart[4][32];
    __shared__ float brSh[8];

    // stage LDS weight tier (pre-packed in exact LDS layout)
    {
        const float4* g4 = reinterpret_cast<const float4*>(WLDS);
        float4* w4 = reinterpret_cast<float4*>(wlds);
        #pragma unroll
        for (int it = 0; it < 18; ++it) w4[tid + it * 512] = g4[tid + it * 512];
    }
    if (lower) mem[i] = 0.f;
    __syncthreads();

    const v4f* wbase =
        reinterpret_cast<const v4f*>(wlds) + (size_t)wv8 * (18 * 64) + lane;
    const v4f* gl = reinterpret_cast<const v4f*>(WGL) + tid;

    const float* WTMh = WTMT + (size_t)h * 128 * D + i;
    const float* WTBh = WTBT + (size_t)h * 128 * D + i;
    const float* WBTh = WBTT + (size_t)h * 128 * D + i;
    const float* M1h  = M1T  + (size_t)h * 128 * D + i;

    int rel = 0;

    #pragma unroll 1
    for (int t = 0; t < SEQ; ++t) {
        // ---- top step: outp = tanh(TW[t] + RV[rel] + Wt_m @ mem) ----
        psA[h][i] = mv_half(WTMh, mem + h * 128);
        __syncthreads();
        if (lower) {
            float tot = psA[0][i] + psA[1][i] +
                        TW[t * D + i] + RV[rel * D + i];
            float outp = tanhf(tot);
            outv[i] = outp;
            #pragma unroll 2
            for (int r = 0; r < NREL; ++r) {
                float pp = outp * Wp[r * D + i];
                #pragma unroll
                for (int off = 32; off; off >>= 1) pp += __shfl_xor(pp, off);
                if (lane == 0) lpart[lwv][r] = pp;
            }
        }
        __syncthreads();
        float lv = -FLT_MAX;
        if (lane < NREL)
            lv = lpart[0][lane] + lpart[1][lane] + lpart[2][lane] +
                 lpart[3][lane] + bp[lane];
        int am; float pm;
        grp_smax<32>(lv, NREL, lane, am, pm);
        if (tid == 0) { out[t] = (float)am; out[SEQ + t] = pm; }
        const int action = am;   // wave-uniform

        if (action > 0) {
            rel = action;
            // memb0 = Wtb@outp + btb
            psA[h][i] = mv_half(WTBh, outv + h * 128);
            const size_t wb0 = (size_t)(action - 1) * NENT * D;
            for (int k = tid; k < NENT * D; k += 512) WrSh[k] = Wpl[wb0 + k];
            if (tid < NENT) brSh[tid] = bpl[(action - 1) * NENT + tid];
            __syncthreads();
            if (lower) xbuf[0][i] = psA[0][i] + psA[1][i] + btb[i];
            __syncthreads();
            // btm = M1@outp + c1  (tgt matvec folded away)
            psA[h][i] = mv_half(M1h, outv + h * 128);
            __syncthreads();
            float btm = 0.f, bwc = 0.f, evn = 0.f;
            if (lower) {
                btm = psA[0][i] + psA[1][i] + c1v[i];
                bwc = BW[i];          // prefetch BW row 0
                evn = EV[i];          // prefetch EV row 0 (ab starts 0)
            }
            __syncthreads();

            int p = 0, ab = 0;
            #pragma unroll 1
            for (int s = 0; s < SEQ; ++s) {
                // -- issue the 14 L2-tier weight loads (coalesced, pinned) --
                const v4f* glv = gl;
                asm volatile("" : "+v"(glv));   // defeat LICM: not hoistable
                v4f g0  = glv[0 * 512],  g1  = glv[1 * 512],
                    g2  = glv[2 * 512],  g3  = glv[3 * 512],
                    g4  = glv[4 * 512],  g5  = glv[5 * 512],
                    g6  = glv[6 * 512],  g7  = glv[7 * 512],
                    g8  = glv[8 * 512],  g9  = glv[9 * 512],
                    g10 = glv[10 * 512], g11 = glv[11 * 512],
                    g12 = glv[12 * 512], g13 = glv[13 * 512];
                __builtin_amdgcn_sched_barrier(0);

                const v4f* xb = reinterpret_cast<const v4f*>(xbuf[p] + h * 128);
                v2f A0 = {0.f, 0.f}, A1 = {0.f, 0.f},
                    A2 = {0.f, 0.f}, A3 = {0.f, 0.f};
                // LDS tier k=56..127 (18 f4), fenced 4-f4 chunks
                LC(0) LC(4) LC(8) LC(12)
                { v4f la = wbase[16 * 64], lb = wbase[17 * 64];
                  FMA_AB(la, xb[30]) FMA_CD(lb, xb[31]) }
                __builtin_amdgcn_sched_barrier(0);
                // L2 tier k=0..55, consumed last (latency hidden by LDS work)
                FMA_AB(g0,  xb[0])  FMA_CD(g1,  xb[1])
                FMA_AB(g2,  xb[2])  FMA_CD(g3,  xb[3])
                __builtin_amdgcn_sched_barrier(0);
                FMA_AB(g4,  xb[4])  FMA_CD(g5,  xb[5])
                FMA_AB(g6,  xb[6])  FMA_CD(g7,  xb[7])
                __builtin_amdgcn_sched_barrier(0);
                FMA_AB(g8,  xb[8])  FMA_CD(g9,  xb[9])
                FMA_AB(g10, xb[10]) FMA_CD(g11, xb[11])
                __builtin_amdgcn_sched_barrier(0);
                FMA_AB(g12, xb[12]) FMA_CD(g13, xb[13])
                v2f AS = (A0 + A1) + (A2 + A3);
                float ms = AS.x + AS.y;
                psA[h][i] = ms;
                __syncthreads();                       // barrier 1
                if (lower) {
                    float tot = ms + psA[1][i] + bwc + evn + btm;
                    float ob = tanhf(tot);
                    xbuf[p ^ 1][i] = ob;
                    #pragma unroll
                    for (int r = 0; r < NENT; ++r) {
                        float pp = ob * WrSh[r * D + i];
                        #pragma unroll
                        for (int off = 32; off; off >>= 1)
                            pp += __shfl_xor(pp, off);
                        if (lane == 0) lpart[lwv][r] = pp;
                    }
                }
                __syncthreads();                       // barrier 2
                float lv2 = -FLT_MAX;
                if (lane < NENT)
                    lv2 = lpart[0][lane] + lpart[1][lane] + lpart[2][lane] +
                          lpart[3][lane] + brSh[lane];
                int am2; float pm2;
                grp_smax<8>(lv2, NENT, lane, am2, pm2);
                if (tid == 0) {
                    out[2 * SEQ + t * SEQ + s] = (float)am2;
                    out[2 * SEQ + SEQ * SEQ + t * SEQ + s] = pm2;
                }
                ab = am2;        // wave-uniform register
                if (lower) {
                    // prefetch next step's BW row and EV row (hidden under
                    // the next matvec; both L2-resident)
                    int sn = (s + 1 < SEQ) ? s + 1 : s;
                    bwc = BW[sn * D + i];
                    evn = EV[ab * D + i];
                }
                p ^= 1;
            }
            // mem = Wbt @ membf + bbt
            psA[h][i] = mv_half(WBTh, xbuf[p] + h * 128);
            __syncthreads();
            if (lower) mem[i] = psA[0][i] + psA[1][i] + bbt[i];
            __syncthreads();
        } else {
            if (lower) mem[i] = outv[i];
            if (tid < SEQ) {
                out[2 * SEQ + t * SEQ + tid] = 0.f;
                out[2 * SEQ + SEQ * SEQ + t * SEQ + tid] = 0.f;
            }
            __syncthreads();
        }
    }
}

// ---------------------------------------------------------------------------
extern "C" void kernel_launch(void* const* d_in, const int* in_sizes, int n_in,
                              void* d_out, int out_size, void* d_ws, size_t ws_size,
                              hipStream_t stream)
{
    (void)in_sizes; (void)n_in; (void)out_size; (void)ws_size;
    const int*   text       = (const int*)  d_in[0];
    const float* wordvector = (const float*)d_in[1];
    const float* relvec     = (const float*)d_in[2];
    const float* entvec     = (const float*)d_in[3];
    const float* WihL = (const float*)d_in[4];  const float* WhhL = (const float*)d_in[5];
    const float* bihL = (const float*)d_in[6];  const float* bhhL = (const float*)d_in[7];
    const float* WihR = (const float*)d_in[8];  const float* WhhR = (const float*)d_in[9];
    const float* bihR = (const float*)d_in[10]; const float* bhhR = (const float*)d_in[11];
    const float* Wt   = (const float*)d_in[12]; const float* bt   = (const float*)d_in[13];
    const float* Wp   = (const float*)d_in[14]; const float* bp   = (const float*)d_in[15];
    const float* Wb   = (const float*)d_in[16]; const float* bb   = (const float*)d_in[17];
    const float* Wpl  = (const float*)d_in[18]; const float* bpl  = (const float*)d_in[19];
    const float* Wtt  = (const float*)d_in[20]; const float* btt  = (const float*)d_in[21];
    const float* Wtb  = (const float*)d_in[22]; const float* btb  = (const float*)d_in[23];
    const float* Wbt  = (const float*)d_in[24]; const float* bbt  = (const float*)d_in[25];

    float* ws = (float*)d_ws;
    size_t o = 0;
    auto take = [&](size_t n) { float* p = ws + o; o += n; return p; };
    float* XGF    = take(SEQ * G);
    float* XGB    = take(SEQ * G);
    float* WHLT   = take(D * G);
    float* WHRT   = take(D * G);
    float* WORDIN = take(SEQ * 2 * D);
    float* TW     = take(SEQ * D);
    float* BW     = take(SEQ * D);
    float* RVb    = take(NREL * D);
    float* EVb    = take(NENT * D);
    float* WTWT   = take(2 * D * D);
    float* WTRT   = take(D * D);
    float* WTMT   = take(D * D);
    float* WBWT   = take(2 * D * D);
    float* WBET   = take(D * D);
    float* WBGT   = take(D * D);
    float* WTBT   = take(D * D);
    float* WBTT   = take(D * D);
    float* M1T    = take(D * D);
    float* C1     = take(D);
    float* WLDS   = take(512 * 72);      // LDS-tier pack (LDS layout order)
    float* WGL    = take(512 * 56);      // L2-tier pack (coalesced layout)

    auto tr = [&](const float* in, float* outp, int rows, int cols, int stride, int off) {
        int n = rows * cols;
        k_trans<<<(n + 255) / 256, 256, 0, stream>>>(in, outp, rows, cols, stride, off);
    };
    tr(WhhL, WHLT, G, D, D, 0);          // WHLT[k*G + j] = WhhL[j][k]
    tr(WhhR, WHRT, G, D, D, 0);
    tr(Wt,  WTWT, D, 2 * D, G, 0);       // word part of Wt
    tr(Wt,  WTRT, D, D, G, 512);         // relvec part
    tr(Wt,  WTMT, D, D, G, 768);         // mem part
    tr(Wb,  WBWT, D, 2 * D, 5 * D, 0);   // word part of Wb
    tr(Wb,  WBET, D, D, 5 * D, 512);     // entvec part
    tr(Wb,  WBGT, D, D, 5 * D, 1024);    // target part (feeds M1/c1)
    tr(Wtb, WTBT, D, D, D, 0);
    tr(Wbt, WBTT, D, D, D, 0);

    k_m1<<<D, D, 0, stream>>>(WBGT, Wtt, M1T);
    k_c1<<<1, D, 0, stream>>>(WBGT, btt, C1);
    k_packBl<<<(512 * 72 + 255) / 256, 256, 0, stream>>>(Wb, WLDS);
    k_packBg<<<(512 * 56 + 255) / 256, 256, 0, stream>>>(Wb, WGL);

    k_xg<<<SEQ, 1024, 0, stream>>>(text, wordvector, WihL, bihL, bhhL, XGF);
    k_xg<<<SEQ, 1024, 0, stream>>>(text, wordvector, WihR, bihR, bhhR, XGB);
    k_lstm<<<2, 1024, 0, stream>>>(XGF, XGB, WHLT, WHRT, WORDIN);
    k_prep2<<<SEQ + NREL + NENT, 256, 0, stream>>>(WORDIN, WTWT, WBWT, WTRT, WBET,
                                                   relvec, entvec, bt, bb,
                                                   TW, BW, RVb, EVb);
    k_mainB<<<1, 512, 0, stream>>>(TW, BW, RVb, EVb, WTMT, WTBT, WBTT, M1T, C1,
                                   WLDS, WGL, Wp, bp, Wpl, bpl, btb, bbt,
                                   (float*)d_out);
}

// Round 14
// 54047.003 us; speedup vs baseline: 1.1674x; 1.1674x over previous
//
#include <hip/hip_runtime.h>
#include <float.h>

constexpr int SEQ  = 128;   // sentence length T
constexpr int D    = 256;   // DIM / STATEDIM
constexpr int G    = 1024;  // 4*DIM gate width
constexpr int NREL = 26;    // REL_COUNT + 1
constexpr int NENT = 7;

typedef float v2f __attribute__((ext_vector_type(2)));
typedef float v4f __attribute__((ext_vector_type(4)));

// ---------------------------------------------------------------------------
// Generic strided transpose: out[k*rows + i] = in[i*in_stride + in_off + k]
// ---------------------------------------------------------------------------
__global__ void k_trans(const float* __restrict__ in, float* __restrict__ out,
                        int rows, int cols, int in_stride, int in_off)
{
    int idx = blockIdx.x * 256 + threadIdx.x;
    if (idx >= rows * cols) return;
    int i = idx % rows;
    int k = idx / rows;
    out[idx] = in[(size_t)i * in_stride + in_off + k];
}

// ---------------------------------------------------------------------------
// xg[t][j] = bih[j] + bhh[j] + sum_k wordvector[text[t]][k] * Wih[j][k]
// ---------------------------------------------------------------------------
__global__ __launch_bounds__(1024) void k_xg(
    const int* __restrict__ text, const float* __restrict__ wv,
    const float* __restrict__ Wih, const float* __restrict__ bih,
    const float* __restrict__ bhh, float* __restrict__ xg)
{
    int t = blockIdx.x, j = threadIdx.x;
    const float* x  = wv + (size_t)text[t] * D;
    const float* wr = Wih + (size_t)j * D;
    float acc = bih[j] + bhh[j];
    for (int k = 0; k < D; ++k) acc += x[k] * wr[k];
    xg[t * G + j] = acc;
}

// ---------------------------------------------------------------------------
// Sequential LSTM, one block per direction (grid=2), 1024 threads.
// ---------------------------------------------------------------------------
__global__ __launch_bounds__(1024) void k_lstm(
    const float* __restrict__ xgF, const float* __restrict__ xgB,
    const float* __restrict__ WHTF, const float* __restrict__ WHTB,
    float* __restrict__ wordin)
{
    int dir = blockIdx.x;
    const float* xg  = dir ? xgB  : xgF;
    const float* WHT = dir ? WHTB : WHTF;
    __shared__ float h[D], c[D], g[G];
    int j = threadIdx.x;
    if (j < D) { h[j] = 0.f; c[j] = 0.f; }
    __syncthreads();
    for (int s = 0; s < SEQ; ++s) {
        int t = dir ? (SEQ - 1 - s) : s;
        float acc = xg[t * G + j];
        for (int k = 0; k < D; ++k) acc += WHT[k * G + j] * h[k];
        g[j] = acc;
        __syncthreads();
        if (j < D) {
            float si = 1.f / (1.f + expf(-g[j]));
            float sf = 1.f / (1.f + expf(-g[D + j]));
            float gg = tanhf(g[2 * D + j]);
            float so = 1.f / (1.f + expf(-g[3 * D + j]));
            float cn = sf * c[j] + si * gg;
            float hn = so * tanhf(cn);
            c[j] = cn; h[j] = hn;
            wordin[t * (2 * D) + dir * D + j] = hn;
        }
        __syncthreads();
    }
}

// ---------------------------------------------------------------------------
// Parallel precompute after LSTM (TW/BW per word, RV per relation, EV per ent)
// ---------------------------------------------------------------------------
__global__ __launch_bounds__(256) void k_prep2(
    const float* __restrict__ wordin,
    const float* __restrict__ WTWT, const float* __restrict__ WBWT,
    const float* __restrict__ WTRT, const float* __restrict__ WBET,
    const float* __restrict__ relvec, const float* __restrict__ entvec,
    const float* __restrict__ btv, const float* __restrict__ bbv,
    float* __restrict__ TW, float* __restrict__ BW,
    float* __restrict__ RV, float* __restrict__ EV)
{
    int b = blockIdx.x, i = threadIdx.x;
    if (b < SEQ) {
        const float* w = wordin + b * (2 * D);
        float a1 = btv[i], a2 = bbv[i];
        for (int j = 0; j < 2 * D; ++j) {
            float wv = w[j];
            a1 += wv * WTWT[j * D + i];
            a2 += wv * WBWT[j * D + i];
        }
        TW[b * D + i] = a1;
        BW[b * D + i] = a2;
    } else if (b < SEQ + NREL) {
        int r = b - SEQ;
        const float* x = relvec + r * D;
        float a = 0.f;
        for (int k = 0; k < D; ++k) a += x[k] * WTRT[k * D + i];
        RV[r * D + i] = a;
    } else {
        int e = b - SEQ - NREL;
        const float* x = entvec + e * D;
        float a = 0.f;
        for (int k = 0; k < D; ++k) a += x[k] * WBET[k * D + i];
        EV[e * D + i] = a;
    }
}

// ---------------------------------------------------------------------------
// M1T[j*D + i] = sum_k WBGT[k*D+i] * Wtt[k*D+j]   (M1 = Wb_target @ Wtt)
// ---------------------------------------------------------------------------
__global__ __launch_bounds__(256) void k_m1(
    const float* __restrict__ WBGT, const float* __restrict__ Wtt,
    float* __restrict__ M1T)
{
    int j = blockIdx.x, i = threadIdx.x;
    float a = 0.f;
    for (int k = 0; k < D; ++k) a = fmaf(WBGT[k * D + i], Wtt[k * D + j], a);
    M1T[j * D + i] = a;
}

// c1[i] = sum_k WBGT[k*D+i] * btt[k]
__global__ __launch_bounds__(256) void k_c1(
    const float* __restrict__ WBGT, const float* __restrict__ btt,
    float* __restrict__ c1)
{
    int i = threadIdx.x;
    float a = 0.f;
    for (int k = 0; k < D; ++k) a = fmaf(WBGT[k * D + i], btt[k], a);
    c1[i] = a;
}

// ---------------------------------------------------------------------------
// Packs for the 3-tier bot weight matvec (512 threads, tid = h*256+i):
//  reg tier  q=0..31 : WREG[tid*32 + q]       = Wb[i][768 + h*128 + q]
//  L2 tier   n=0..5  : f4 slot n*512 + tid    = Wb[i][768 + h*128 + 32 + 4n+c]
//  LDS tier  j=0..17 : f4 slot (w*18+j)*64+l  = Wb[i][768 + h*128 + 56 + 4j+c]
// ---------------------------------------------------------------------------
__global__ __launch_bounds__(256) void k_packCr(
    const float* __restrict__ Wb, float* __restrict__ WREG)
{
    int e = blockIdx.x * 256 + threadIdx.x;      // 0..16383
    if (e >= 512 * 32) return;
    int tid = e >> 5, q = e & 31;
    int h = tid >> 8, i = tid & 255;
    WREG[e] = Wb[(size_t)i * (5 * D) + 3 * D + h * 128 + q];
}

__global__ __launch_bounds__(256) void k_packCg(
    const float* __restrict__ Wb, float* __restrict__ WGL)
{
    int f = blockIdx.x * 256 + threadIdx.x;      // 0..12287
    if (f >= 512 * 24) return;
    int f4 = f >> 2, c = f & 3;
    int tid = f4 & 511, n = f4 >> 9;
    int h = tid >> 8, i = tid & 255;
    WGL[f] = Wb[(size_t)i * (5 * D) + 3 * D + h * 128 + 32 + 4 * n + c];
}

__global__ __launch_bounds__(256) void k_packCl(
    const float* __restrict__ Wb, float* __restrict__ WLDS)
{
    int f = blockIdx.x * 256 + threadIdx.x;      // 0..36863
    if (f >= 512 * 72) return;
    int f4 = f >> 2, c = f & 3;
    int l = f4 & 63, rest = f4 >> 6;
    int j = rest % 18, w = rest / 18;
    int tid = w * 64 + l;
    int h = tid >> 8, i = tid & 255;
    WLDS[f] = Wb[(size_t)i * (5 * D) + 3 * D + h * 128 + 56 + 4 * j + c];
}

// ---------------------------------------------------------------------------
// Streamed split-k half-matvec (top steps). unroll CAPPED at 8 (R12 lesson:
// a full unroll here spikes pressure and poisons the whole kernel's alloc).
// ---------------------------------------------------------------------------
__device__ inline float mv_half(const float* __restrict__ Wcol,
                                const float* __restrict__ x)
{
    float a0 = 0.f, a1 = 0.f, a2 = 0.f, a3 = 0.f;
    #pragma unroll 8
    for (int kk = 0; kk < 128; kk += 4) {
        a0 = fmaf(Wcol[(kk + 0) * D], x[kk + 0], a0);
        a1 = fmaf(Wcol[(kk + 1) * D], x[kk + 1], a1);
        a2 = fmaf(Wcol[(kk + 2) * D], x[kk + 2], a2);
        a3 = fmaf(Wcol[(kk + 3) * D], x[kk + 3], a3);
    }
    return (a0 + a1) + (a2 + a3);
}

// ---------------------------------------------------------------------------
// Softmax + first-occurrence argmax over n values in lanes 0..n-1 of each
// W-lane group (reference-faithful: p = exp(l-max)/sum, argmax over p).
// ---------------------------------------------------------------------------
template<int W>
__device__ inline void grp_smax(float lv, int n, int lane, int& am, float& pm)
{
    float mx = lv;
    #pragma unroll
    for (int off = W / 2; off; off >>= 1) mx = fmaxf(mx, __shfl_xor(mx, off));
    float e  = (lane < n) ? expf(lv - mx) : 0.f;
    float se = e;
    #pragma unroll
    for (int off = W / 2; off; off >>= 1) se += __shfl_xor(se, off);
    float p  = (lane < n) ? (e / se) : -1.f;
    float q  = p;
    #pragma unroll
    for (int off = W / 2; off; off >>= 1) q = fmaxf(q, __shfl_xor(q, off));
    unsigned long long mask = __ballot(p == q);
    am = __ffsll((long long)mask) - 1;
    pm = q;
}

// FMA helpers: one float4 pair into two v2f accumulators
#define FMA_AB(Wv, Xv)                                                        \
    { v4f xx_ = (Xv);                                                         \
      A0 = __builtin_elementwise_fma((v2f){(Wv).x, (Wv).y},                   \
                                     (v2f){xx_.x, xx_.y}, A0);                \
      A1 = __builtin_elementwise_fma((v2f){(Wv).z, (Wv).w},                   \
                                     (v2f){xx_.z, xx_.w}, A1); }
#define FMA_CD(Wv, Xv)                                                        \
    { v4f xx_ = (Xv);                                                         \
      A2 = __builtin_elementwise_fma((v2f){(Wv).x, (Wv).y},                   \
                                     (v2f){xx_.x, xx_.y}, A2);                \
      A3 = __builtin_elementwise_fma((v2f){(Wv).z, (Wv).w},                   \
                                     (v2f){xx_.z, xx_.w}, A3); }

// one LDS weight chunk: 4 f4 weights x 4 f4 x-broadcast, then a fence
#define LC(j0)                                                                \
    { v4f la = wbase[(j0 + 0) * 64], lb = wbase[(j0 + 1) * 64],               \
          lc = wbase[(j0 + 2) * 64], ld = wbase[(j0 + 3) * 64];               \
      FMA_AB(la, xb[14 + j0 + 0]) FMA_CD(lb, xb[14 + j0 + 1])                 \
      FMA_AB(lc, xb[14 + j0 + 2]) FMA_CD(ld, xb[14 + j0 + 3])                 \
      __builtin_amdgcn_sched_barrier(0); }

// raw barrier: order LDS (lgkmcnt) but do NOT drain vmcnt — global loads
// (g-tier weights, BW/EV prefetch) stay in flight across it. __syncthreads
// would emit s_waitcnt vmcnt(0) and kill all cross-barrier prefetching.
#define BARX()                                                                \
    do { asm volatile("s_waitcnt lgkmcnt(0)" ::: "memory");                   \
         __builtin_amdgcn_s_barrier(); } while (0)

// ---------------------------------------------------------------------------
// Sequential main kernel: 1 block, 512 threads = 8 waves = 2 waves/SIMD.
// R13 proved the storage discipline (VGPR 88, no spill). R14 fixes the
// SCHEDULE: (1) g-tier shrunk 14->6 f4 (L2 stream 114->49 KB/step: single-CU
// L2 port ~64 B/cy made the stream ~1800 cy/step); (2) raw barriers keep
// vmem loads in flight (HIP __syncthreads drains vmcnt(0) -> R13's g-loads
// and BW/EV prefetches never overlapped anything); (3) g-loads issue one
// full step ahead -> ~2500 cy cover, HBM misses hidden.
// ---------------------------------------------------------------------------
__global__ __launch_bounds__(512)
void k_mainC(
    const float* __restrict__ TW,   const float* __restrict__ BW,
    const float* __restrict__ RV,   const float* __restrict__ EV,
    const float* __restrict__ WTMT, const float* __restrict__ WTBT,
    const float* __restrict__ WBTT, const float* __restrict__ M1T,
    const float* __restrict__ c1v,  const float* __restrict__ WREG,
    const float* __restrict__ WLDS, const float* __restrict__ WGL,
    const float* __restrict__ Wp,   const float* __restrict__ bp,
    const float* __restrict__ Wpl,  const float* __restrict__ bpl,
    const float* __restrict__ btb,  const float* __restrict__ bbt,
    float* __restrict__ out)
{
    const int tid  = threadIdx.x;
    const int lane = tid & 63;
    const int wv8  = tid >> 6;        // wave id 0..7
    const int lwv  = wv8 & 3;         // wave id within half
    const int h    = tid >> 8;        // k-half 0..1
    const int i    = tid & 255;       // output index
    const bool lower = (tid < 256);

    // --- LDS (161,312 B total) ---
    __shared__ __align__(16) float wlds[512 * 72];        // 147,456 B
    __shared__ __align__(16) float xbuf[2][D];
    __shared__ __align__(16) float psA[2][D];
    __shared__ __align__(16) float mem[D], outv[D];
    __shared__ __align__(16) float WrSh[NENT * D];
    __shared__ float lpart[4][32];
    __shared__ float brSh[8];

    // stage LDS weight tier (pre-packed in exact LDS layout)
    {
        const float4* g4s = reinterpret_cast<const float4*>(WLDS);
        float4* w4 = reinterpret_cast<float4*>(wlds);
        #pragma unroll
        for (int it = 0; it < 18; ++it) w4[tid + it * 512] = g4s[tid + it * 512];
    }
    if (lower) mem[i] = 0.f;

    // register tier: 8 NAMED float4 (32 VGPRs)
    const v4f* r4 = reinterpret_cast<const v4f*>(WREG) + tid * 8;
    v4f wr0 = r4[0], wr1 = r4[1], wr2 = r4[2], wr3 = r4[3];
    v4f wr4 = r4[4], wr5 = r4[5], wr6 = r4[6], wr7 = r4[7];

    __syncthreads();

    const v4f* wbase =
        reinterpret_cast<const v4f*>(wlds) + (size_t)wv8 * (18 * 64) + lane;
    const v4f* gl = reinterpret_cast<const v4f*>(WGL) + tid;

    const float* WTMh = WTMT + (size_t)h * 128 * D + i;
    const float* WTBh = WTBT + (size_t)h * 128 * D + i;
    const float* WBTh = WBTT + (size_t)h * 128 * D + i;
    const float* M1h  = M1T  + (size_t)h * 128 * D + i;

    int rel = 0;

    #pragma unroll 1
    for (int t = 0; t < SEQ; ++t) {
        // ---- top step: outp = tanh(TW[t] + RV[rel] + Wt_m @ mem) ----
        psA[h][i] = mv_half(WTMh, mem + h * 128);
        __syncthreads();
        if (lower) {
            float tot = psA[0][i] + psA[1][i] +
                        TW[t * D + i] + RV[rel * D + i];
            float outp = tanhf(tot);
            outv[i] = outp;
            #pragma unroll 2
            for (int r = 0; r < NREL; ++r) {
                float pp = outp * Wp[r * D + i];
                #pragma unroll
                for (int off = 32; off; off >>= 1) pp += __shfl_xor(pp, off);
                if (lane == 0) lpart[lwv][r] = pp;
            }
        }
        __syncthreads();
        float lv = -FLT_MAX;
        if (lane < NREL)
            lv = lpart[0][lane] + lpart[1][lane] + lpart[2][lane] +
                 lpart[3][lane] + bp[lane];
        int am; float pm;
        grp_smax<32>(lv, NREL, lane, am, pm);
        if (tid == 0) { out[t] = (float)am; out[SEQ + t] = pm; }
        const int action = am;   // wave-uniform

        if (action > 0) {
            rel = action;
            // memb0 = Wtb@outp + btb
            psA[h][i] = mv_half(WTBh, outv + h * 128);
            const size_t wb0 = (size_t)(action - 1) * NENT * D;
            for (int k = tid; k < NENT * D; k += 512) WrSh[k] = Wpl[wb0 + k];
            if (tid < NENT) brSh[tid] = bpl[(action - 1) * NENT + tid];
            __syncthreads();
            if (lower) xbuf[0][i] = psA[0][i] + psA[1][i] + btb[i];
            __syncthreads();
            // btm = M1@outp + c1  (tgt matvec folded away)
            psA[h][i] = mv_half(M1h, outv + h * 128);
            __syncthreads();
            float btm = 0.f, bwc = 0.f, evn = 0.f;
            if (lower) {
                btm = psA[0][i] + psA[1][i] + c1v[i];
                bwc = BW[i];          // prefetch BW row 0
                evn = EV[i];          // prefetch EV row 0 (ab starts 0)
            }
            __syncthreads();

            // prologue: issue step-0 g-tier loads (pinned against LICM)
            v4f g0, g1, g2, g3, g4, g5;
            {
                const v4f* glv = gl;
                asm volatile("" : "+v"(glv));
                g0 = glv[0 * 512]; g1 = glv[1 * 512]; g2 = glv[2 * 512];
                g3 = glv[3 * 512]; g4 = glv[4 * 512]; g5 = glv[5 * 512];
            }

            int p = 0, ab = 0;
            #pragma unroll 1
            for (int s = 0; s < SEQ; ++s) {
                const v4f* xb = reinterpret_cast<const v4f*>(xbuf[p] + h * 128);
                v2f A0 = {0.f, 0.f}, A1 = {0.f, 0.f},
                    A2 = {0.f, 0.f}, A3 = {0.f, 0.f};
                // LDS tier k=56..127 (18 f4), fenced 4-f4 chunks
                LC(0) LC(4) LC(8) LC(12)
                { v4f la = wbase[16 * 64], lb = wbase[17 * 64];
                  FMA_AB(la, xb[30]) FMA_CD(lb, xb[31]) }
                __builtin_amdgcn_sched_barrier(0);
                // reg tier k=0..31
                FMA_AB(wr0, xb[0]) FMA_CD(wr1, xb[1])
                FMA_AB(wr2, xb[2]) FMA_CD(wr3, xb[3])
                __builtin_amdgcn_sched_barrier(0);
                FMA_AB(wr4, xb[4]) FMA_CD(wr5, xb[5])
                FMA_AB(wr6, xb[6]) FMA_CD(wr7, xb[7])
                __builtin_amdgcn_sched_barrier(0);
                // g tier k=32..55 (loads issued LAST step -> latency hidden)
                FMA_AB(g0, xb[8])  FMA_CD(g1, xb[9])
                FMA_AB(g2, xb[10]) FMA_CD(g3, xb[11])
                FMA_AB(g4, xb[12]) FMA_CD(g5, xb[13])
                // reissue g for next step; stays in flight across barriers
                {
                    const v4f* glv = gl;
                    asm volatile("" : "+v"(glv));
                    g0 = glv[0 * 512]; g1 = glv[1 * 512]; g2 = glv[2 * 512];
                    g3 = glv[3 * 512]; g4 = glv[4 * 512]; g5 = glv[5 * 512];
                }
                v2f AS = (A0 + A1) + (A2 + A3);
                float ms = AS.x + AS.y;
                psA[h][i] = ms;
                BARX();                                // barrier 1 (raw)
                if (lower) {
                    float tot = ms + psA[1][i] + bwc + evn + btm;
                    float ob = tanhf(tot);
                    xbuf[p ^ 1][i] = ob;
                    #pragma unroll
                    for (int r = 0; r < NENT; ++r) {
                        float pp = ob * WrSh[r * D + i];
                        #pragma unroll
                        for (int off = 32; off; off >>= 1)
                            pp += __shfl_xor(pp, off);
                        if (lane == 0) lpart[lwv][r] = pp;
                    }
                }
                BARX();                                // barrier 2 (raw)
                float lv2 = -FLT_MAX;
                if (lane < NENT)
                    lv2 = lpart[0][lane] + lpart[1][lane] + lpart[2][lane] +
                          lpart[3][lane] + brSh[lane];
                int am2; float pm2;
                grp_smax<8>(lv2, NENT, lane, am2, pm2);
                if (tid == 0) {
                    out[2 * SEQ + t * SEQ + s] = (float)am2;
                    out[2 * SEQ + SEQ * SEQ + t * SEQ + s] = pm2;
                }
                ab = am2;        // wave-uniform register
                if (lower) {
                    // prefetch next step's BW/EV rows; in flight across BARX
                    int sn = (s + 1 < SEQ) ? s + 1 : s;
                    bwc = BW[sn * D + i];
                    evn = EV[ab * D + i];
                }
                p ^= 1;
            }
            // mem = Wbt @ membf + bbt
            psA[h][i] = mv_half(WBTh, xbuf[p] + h * 128);
            __syncthreads();
            if (lower) mem[i] = psA[0][i] + psA[1][i] + bbt[i];
            __syncthreads();
        } else {
            if (lower) mem[i] = outv[i];
            if (tid < SEQ) {
                out[2 * SEQ + t * SEQ + tid] = 0.f;
                out[2 * SEQ + SEQ * SEQ + t * SEQ + tid] = 0.f;
            }
            __syncthreads();
        }
    }
}

// ---------------------------------------------------------------------------
extern "C" void kernel_launch(void* const* d_in, const int* in_sizes, int n_in,
                              void* d_out, int out_size, void* d_ws, size_t ws_size,
                              hipStream_t stream)
{
    (void)in_sizes; (void)n_in; (void)out_size; (void)ws_size;
    const int*   text       = (const int*)  d_in[0];
    const float* wordvector = (const float*)d_in[1];
    const float* relvec     = (const float*)d_in[2];
    const float* entvec     = (const float*)d_in[3];
    const float* WihL = (const float*)d_in[4];  const float* WhhL = (const float*)d_in[5];
    const float* bihL = (const float*)d_in[6];  const float* bhhL = (const float*)d_in[7];
    const float* WihR = (const float*)d_in[8];  const float* WhhR = (const float*)d_in[9];
    const float* bihR = (const float*)d_in[10]; const float* bhhR = (const float*)d_in[11];
    const float* Wt   = (const float*)d_in[12]; const float* bt   = (const float*)d_in[13];
    const float* Wp   = (const float*)d_in[14]; const float* bp   = (const float*)d_in[15];
    const float* Wb   = (const float*)d_in[16]; const float* bb   = (const float*)d_in[17];
    const float* Wpl  = (const float*)d_in[18]; const float* bpl  = (const float*)d_in[19];
    const float* Wtt  = (const float*)d_in[20]; const float* btt  = (const float*)d_in[21];
    const float* Wtb  = (const float*)d_in[22]; const float* btb  = (const float*)d_in[23];
    const float* Wbt  = (const float*)d_in[24]; const float* bbt  = (const float*)d_in[25];

    float* ws = (float*)d_ws;
    size_t o = 0;
    auto take = [&](size_t n) { float* p = ws + o; o += n; return p; };
    float* XGF    = take(SEQ * G);
    float* XGB    = take(SEQ * G);
    float* WHLT   = take(D * G);
    float* WHRT   = take(D * G);
    float* WORDIN = take(SEQ * 2 * D);
    float* TW     = take(SEQ * D);
    float* BW     = take(SEQ * D);
    float* RVb    = take(NREL * D);
    float* EVb    = take(NENT * D);
    float* WTWT   = take(2 * D * D);
    float* WTRT   = take(D * D);
    float* WTMT   = take(D * D);
    float* WBWT   = take(2 * D * D);
    float* WBET   = take(D * D);
    float* WBGT   = take(D * D);
    float* WTBT   = take(D * D);
    float* WBTT   = take(D * D);
    float* M1T    = take(D * D);
    float* C1     = take(D);
    float* WREG   = take(512 * 32);      // register-tier pack (k 0..31)
    float* WLDS   = take(512 * 72);      // LDS-tier pack (k 56..127)
    float* WGL    = take(512 * 24);      // L2-tier pack (k 32..55)

    auto tr = [&](const float* in, float* outp, int rows, int cols, int stride, int off) {
        int n = rows * cols;
        k_trans<<<(n + 255) / 256, 256, 0, stream>>>(in, outp, rows, cols, stride, off);
    };
    tr(WhhL, WHLT, G, D, D, 0);          // WHLT[k*G + j] = WhhL[j][k]
    tr(WhhR, WHRT, G, D, D, 0);
    tr(Wt,  WTWT, D, 2 * D, G, 0);       // word part of Wt
    tr(Wt,  WTRT, D, D, G, 512);         // relvec part
    tr(Wt,  WTMT, D, D, G, 768);         // mem part
    tr(Wb,  WBWT, D, 2 * D, 5 * D, 0);   // word part of Wb
    tr(Wb,  WBET, D, D, 5 * D, 512);     // entvec part
    tr(Wb,  WBGT, D, D, 5 * D, 1024);    // target part (feeds M1/c1)
    tr(Wtb, WTBT, D, D, D, 0);
    tr(Wbt, WBTT, D, D, D, 0);

    k_m1<<<D, D, 0, stream>>>(WBGT, Wtt, M1T);
    k_c1<<<1, D, 0, stream>>>(WBGT, btt, C1);
    k_packCr<<<(512 * 32 + 255) / 256, 256, 0, stream>>>(Wb, WREG);
    k_packCl<<<(512 * 72 + 255) / 256, 256, 0, stream>>>(Wb, WLDS);
    k_packCg<<<(512 * 24 + 255) / 256, 256, 0, stream>>>(Wb, WGL);

    k_xg<<<SEQ, 1024, 0, stream>>>(text, wordvector, WihL, bihL, bhhL, XGF);
    k_xg<<<SEQ, 1024, 0, stream>>>(text, wordvector, WihR, bihR, bhhR, XGB);
    k_lstm<<<2, 1024, 0, stream>>>(XGF, XGB, WHLT, WHRT, WORDIN);
    k_prep2<<<SEQ + NREL + NENT, 256, 0, stream>>>(WORDIN, WTWT, WBWT, WTRT, WBET,
                                                   relvec, entvec, bt, bb,
                                                   TW, BW, RVb, EVb);
    k_mainC<<<1, 512, 0, stream>>>(TW, BW, RVb, EVb, WTMT, WTBT, WBTT, M1T, C1,
                                   WREG, WLDS, WGL, Wp, bp, Wpl, bpl, btb, bbt,
                                   (float*)d_out);
}